// Round 3
// baseline (1267.936 us; speedup 1.0000x reference)
//
#include <hip/hip_runtime.h>

#define EPS 1e-5f

constexpr int Bb  = 128;     // batches
constexpr int Np  = 8192;    // points per batch
constexpr int C1  = 64, C2 = 128, C3 = 256;
constexpr int P   = 32;      // points per chunk
constexpr int CHUNKS = 8;    // chunks per block
constexpr int PTS_PER_BLOCK = P * CHUNKS;          // 256
constexpr int BLK_PER_BATCH = Np / PTS_PER_BLOCK;  // 32

typedef __attribute__((ext_vector_type(8))) short short8v;  // 8 bf16 = 4 VGPR
typedef __attribute__((ext_vector_type(4))) float f32x4;    // MFMA acc

__device__ __forceinline__ ushort f2bf(float f) {
  uint x = __float_as_uint(f);
  uint r = (x + 0x7fffu + ((x >> 16) & 1u)) >> 16;   // RNE
  return (ushort)r;
}

// ---------------------------------------------------------------------------
// prepW3: W3 [128][256] f32  ->  W3s bf16 in B-fragment order for
// v_mfma_f32_16x16x32_bf16:  W3s[nt][kk][lane][i] = W3[kk*32+(lane>>4)*8+i]
//                                                     [nt*16+(lane&15)]
// (nt = 16 N-tiles of 16 cols, kk = 4 K-steps of 32)
// ---------------------------------------------------------------------------
__global__ __launch_bounds__(256) void prepW3(const float* __restrict__ W3,
                                              ushort* __restrict__ W3s) {
  const int idx = blockIdx.x * 256 + threadIdx.x;    // 0..32767
  const int i  = idx & 7;
  const int l  = (idx >> 3) & 63;
  const int kk = (idx >> 9) & 3;
  const int nt = idx >> 11;
  const int k  = kk * 32 + (l >> 4) * 8 + i;
  const int n  = nt * 16 + (l & 15);
  W3s[idx] = f2bf(W3[k * C3 + n]);
}

// ---------------------------------------------------------------------------
// Stage A: fused per-point MLP. Layers 1-2 vector fp32 (channels across
// lanes, shfl LN). Layer 3 = bf16 MFMA 16x16x32: M=32 (chunk), N=256, K=128.
// Wave w owns N-quarter w (cols w*64..w*64+63, 4 N-tiles) x 2 M-groups.
// h2 staged bf16 in LDS with XOR swizzle byte^=(row&7)<<4 (kills the
// stride-256B 16-way bank conflict on ds_read_b128 A-fragments).
// ---------------------------------------------------------------------------
__global__ __launch_bounds__(256) void stageA(
    const float* __restrict__ pc,    // [B][N][3]
    const float* __restrict__ W1, const float* __restrict__ b1,
    const float* __restrict__ g1, const float* __restrict__ be1,
    const float* __restrict__ W2, const float* __restrict__ b2,
    const float* __restrict__ g2, const float* __restrict__ be2,
    const ushort* __restrict__ W3s, const float* __restrict__ b3,
    const float* __restrict__ g3, const float* __restrict__ be3,
    float* __restrict__ pooled)      // [B][C3], pre-zeroed, int-bits atomicMax
{
  __shared__ float  s_x[P][4];          // chunk's raw points
  __shared__ float  s_h1[P][C1];        // layer-1 output (post LN+ReLU)
  __shared__ ushort s_h2bf[P * C2];     // layer-2 output, bf16, XOR-swizzled
  __shared__ float  s_red[4][P][2];     // per-wave LN partials (layer 3)
  __shared__ float2 s_mi[P];            // per-row (mean, inv) for layer-3 LN

  const int tid  = threadIdx.x;
  const int lane = tid & 63;
  const int w    = tid >> 6;
  const int pw   = w * 8;               // wave's first point (layers 1-2)
  const int b    = blockIdx.x / BLK_PER_BATCH;
  const int base_pt = (blockIdx.x % BLK_PER_BATCH) * PTS_PER_BLOCK;

  // --- per-thread channel params, layers 1-2 (as before) ---
  const float w1c0 = W1[0*C1 + lane], w1c1 = W1[1*C1 + lane], w1c2 = W1[2*C1 + lane];
  const float b1c = b1[lane], g1c = g1[lane], be1c = be1[lane];

  const int c2 = lane * 2;
  const float b2c0 = b2[c2],  b2c1 = b2[c2+1];
  const float g2c0 = g2[c2],  g2c1 = g2[c2+1];
  const float e2c0 = be2[c2], e2c1 = be2[c2+1];

  // --- layer-3 per-thread params: col(t) = w*64 + t*16 + (lane&15) ---
  float b3c[4], g3c[4], e3c[4];
#pragma unroll
  for (int t = 0; t < 4; ++t) {
    const int col = w * 64 + t * 16 + (lane & 15);
    b3c[t] = b3[col]; g3c[t] = g3[col]; e3c[t] = be3[col];
  }

  // --- W3 B-fragments: resident in registers for the whole kernel ---
  short8v w3f[4][4];                    // [t][kk], 64 VGPR
#pragma unroll
  for (int t = 0; t < 4; ++t) {
    const int nt = w * 4 + t;
#pragma unroll
    for (int kk = 0; kk < 4; ++kk)
      w3f[t][kk] = *(const short8v*)(W3s + ((size_t)((nt * 4 + kk) * 64 + lane)) * 8);
  }

  float runmax[4] = {0.f, 0.f, 0.f, 0.f};   // per-lane col max (ReLU => >=0)

  for (int ch = 0; ch < CHUNKS; ++ch) {
    __syncthreads();                 // prev-iter readers of s_x/s_h1/s_h2bf done
    if (tid < P * 3) {
      const int p = tid / 3, d = tid % 3;
      s_x[p][d] = pc[((size_t)b * Np + base_pt + ch * P + p) * 3 + d];
    }
    __syncthreads();

    // ---- layer 1: 3 -> 64 (vector fp32) ----
    float r1[8];
#pragma unroll
    for (int i = 0; i < 8; ++i)
      r1[i] = w1c0 * s_x[pw+i][0] + w1c1 * s_x[pw+i][1] + w1c2 * s_x[pw+i][2] + b1c;

#pragma unroll
    for (int i = 0; i < 8; ++i) {
      float s = r1[i], q = r1[i] * r1[i];
      for (int m = 1; m < 64; m <<= 1) { s += __shfl_xor(s, m, 64); q += __shfl_xor(q, m, 64); }
      const float mean = s * (1.f/64.f);
      const float var  = q * (1.f/64.f) - mean * mean;
      const float inv  = rsqrtf(var + EPS);
      s_h1[pw+i][lane] = fmaxf((r1[i] - mean) * inv * g1c + be1c, 0.f);
    }
    __syncthreads();

    // ---- layer 2: 64 -> 128 (vector fp32), writes bf16 swizzled LDS ----
    float r2[8][2];
#pragma unroll
    for (int i = 0; i < 8; ++i) { r2[i][0] = 0.f; r2[i][1] = 0.f; }
    for (int kq = 0; kq < C1/4; ++kq) {
      const float2 wa = *(const float2*)&W2[(kq*4+0)*C2 + c2];
      const float2 wb = *(const float2*)&W2[(kq*4+1)*C2 + c2];
      const float2 wc = *(const float2*)&W2[(kq*4+2)*C2 + c2];
      const float2 wd = *(const float2*)&W2[(kq*4+3)*C2 + c2];
#pragma unroll
      for (int i = 0; i < 8; ++i) {
        const float4 hv = *(const float4*)&s_h1[pw+i][kq*4];
        r2[i][0] += hv.x*wa.x + hv.y*wb.x + hv.z*wc.x + hv.w*wd.x;
        r2[i][1] += hv.x*wa.y + hv.y*wb.y + hv.z*wc.y + hv.w*wd.y;
      }
    }
#pragma unroll
    for (int i = 0; i < 8; ++i) {
      const float a0 = r2[i][0] + b2c0, a1 = r2[i][1] + b2c1;
      float s = a0 + a1, q = a0*a0 + a1*a1;
      for (int m = 1; m < 64; m <<= 1) { s += __shfl_xor(s, m, 64); q += __shfl_xor(q, m, 64); }
      const float mean = s * (1.f/128.f);
      const float var  = q * (1.f/128.f) - mean * mean;
      const float inv  = rsqrtf(var + EPS);
      const float h0 = fmaxf((a0 - mean) * inv * g2c0 + e2c0, 0.f);
      const float h1 = fmaxf((a1 - mean) * inv * g2c1 + e2c1, 0.f);
      const int row = pw + i;
      const uint pk = (uint)f2bf(h0) | ((uint)f2bf(h1) << 16);
      const int byte = row * 256 + ((lane * 4) ^ ((row & 7) << 4));
      *(uint*)((char*)s_h2bf + byte) = pk;
    }
    __syncthreads();

    // ---- layer 3: bf16 MFMA, M=32 N=256 K=128 ----
    // A-fragments from swizzled LDS: row = g*16+(lane&15), k = kk*32+(lane>>4)*8+i
    short8v afr[2][4];
#pragma unroll
    for (int g = 0; g < 2; ++g) {
      const int row = g * 16 + (lane & 15);
      const int rb  = row * 256;
      const int sw  = (row & 7) << 4;
#pragma unroll
      for (int kk = 0; kk < 4; ++kk) {
        const int koff = kk * 64 + ((lane >> 4) << 4);
        afr[g][kk] = *(const short8v*)((const char*)s_h2bf + rb + (koff ^ sw));
      }
    }

    f32x4 acc[2][4];
#pragma unroll
    for (int g = 0; g < 2; ++g)
#pragma unroll
      for (int t = 0; t < 4; ++t) {
        acc[g][t] = (f32x4){0.f, 0.f, 0.f, 0.f};
#pragma unroll
        for (int kk = 0; kk < 4; ++kk)
          acc[g][t] = __builtin_amdgcn_mfma_f32_16x16x32_bf16(afr[g][kk], w3f[t][kk], acc[g][t], 0, 0, 0);
      }

    // bias, then LN stats per row (row = g*16 + (lane>>4)*4 + j)
    float sp[2][4], sq[2][4];
#pragma unroll
    for (int g = 0; g < 2; ++g)
#pragma unroll
      for (int j = 0; j < 4; ++j) { sp[g][j] = 0.f; sq[g][j] = 0.f; }
#pragma unroll
    for (int g = 0; g < 2; ++g)
#pragma unroll
      for (int t = 0; t < 4; ++t)
#pragma unroll
        for (int j = 0; j < 4; ++j) {
          const float v = acc[g][t][j] + b3c[t];
          acc[g][t][j] = v;
          sp[g][j] += v; sq[g][j] += v * v;
        }
#pragma unroll
    for (int m = 1; m < 16; m <<= 1)
#pragma unroll
      for (int g = 0; g < 2; ++g)
#pragma unroll
        for (int j = 0; j < 4; ++j) {
          sp[g][j] += __shfl_xor(sp[g][j], m, 64);
          sq[g][j] += __shfl_xor(sq[g][j], m, 64);
        }
    if ((lane & 15) == 0) {
#pragma unroll
      for (int g = 0; g < 2; ++g)
#pragma unroll
        for (int j = 0; j < 4; ++j) {
          const int row = g * 16 + (lane >> 4) * 4 + j;
          s_red[w][row][0] = sp[g][j];
          s_red[w][row][1] = sq[g][j];
        }
    }
    __syncthreads();
    if (tid < P) {
      const float s = s_red[0][tid][0] + s_red[1][tid][0] + s_red[2][tid][0] + s_red[3][tid][0];
      const float q = s_red[0][tid][1] + s_red[1][tid][1] + s_red[2][tid][1] + s_red[3][tid][1];
      const float mean = s * (1.f/256.f);
      const float var  = q * (1.f/256.f) - mean * mean;
      s_mi[tid] = make_float2(mean, rsqrtf(var + EPS));
    }
    __syncthreads();

#pragma unroll
    for (int g = 0; g < 2; ++g) {
      const int r0 = g * 16 + (lane >> 4) * 4;
#pragma unroll
      for (int j = 0; j < 4; ++j) {
        const float2 mi = s_mi[r0 + j];
#pragma unroll
        for (int t = 0; t < 4; ++t) {
          const float h = fmaxf((acc[g][t][j] - mi.x) * mi.y * g3c[t] + e3c[t], 0.f);
          runmax[t] = fmaxf(runmax[t], h);
        }
      }
    }
  }

  // ---- col max across lanes sharing (lane&15), then global atomic ----
#pragma unroll
  for (int t = 0; t < 4; ++t) {
    float v = runmax[t];
    v = fmaxf(v, __shfl_xor(v, 16, 64));
    v = fmaxf(v, __shfl_xor(v, 32, 64));
    if (lane < 16)
      atomicMax((int*)&pooled[b * C3 + w * 64 + t * 16 + lane], __float_as_int(v));
  }
}

// ---------------------------------------------------------------------------
// Stage B: pooled -> LN(pooled@Wp+bp) -> film = pc@Wf+bf -> out = s*img + b
// ---------------------------------------------------------------------------
__global__ __launch_bounds__(256) void stageB(
    const float* __restrict__ pooled,  // [B][256]
    const float* __restrict__ img,     // [B][512]
    const float* __restrict__ Wp, const float* __restrict__ bp,
    const float* __restrict__ gp, const float* __restrict__ bep,
    const float* __restrict__ Wf, const float* __restrict__ bf,
    float* __restrict__ out)           // [B][512]
{
  __shared__ float s_pool[C3];
  __shared__ float s_pc[C3];
  __shared__ float s_red[8];

  const int t = threadIdx.x, b = blockIdx.x;
  const int lane = t & 63, w = t >> 6;

  s_pool[t] = pooled[b * C3 + t];
  __syncthreads();

  float y = bp[t];
  for (int k = 0; k < C3; ++k) y += s_pool[k] * Wp[k * C3 + t];

  float s = y, q = y * y;
  for (int m = 1; m < 64; m <<= 1) { s += __shfl_xor(s, m, 64); q += __shfl_xor(q, m, 64); }
  if (lane == 0) { s_red[w * 2] = s; s_red[w * 2 + 1] = q; }
  __syncthreads();
  s = s_red[0] + s_red[2] + s_red[4] + s_red[6];
  q = s_red[1] + s_red[3] + s_red[5] + s_red[7];
  const float mean = s * (1.f/256.f);
  const float var  = q * (1.f/256.f) - mean * mean;
  const float inv  = rsqrtf(var + EPS);
  s_pc[t] = (y - mean) * inv * gp[t] + bep[t];
  __syncthreads();

  float f0 = bf[t], f1 = bf[256 + t], f2 = bf[512 + t], f3 = bf[768 + t];
  for (int k = 0; k < C3; ++k) {
    const float pv = s_pc[k];
    f0 += pv * Wf[k * 1024 + t];
    f1 += pv * Wf[k * 1024 + 256 + t];
    f2 += pv * Wf[k * 1024 + 512 + t];
    f3 += pv * Wf[k * 1024 + 768 + t];
  }
  out[b * 512 + t]       = f0 * img[b * 512 + t]       + f2;
  out[b * 512 + 256 + t] = f1 * img[b * 512 + 256 + t] + f3;
}

extern "C" void kernel_launch(void* const* d_in, const int* in_sizes, int n_in,
                              void* d_out, int out_size, void* d_ws, size_t ws_size,
                              hipStream_t stream) {
  const float* pc  = (const float*)d_in[0];
  const float* img = (const float*)d_in[1];
  const float* W1  = (const float*)d_in[2];
  const float* b1  = (const float*)d_in[3];
  const float* g1  = (const float*)d_in[4];
  const float* be1 = (const float*)d_in[5];
  const float* W2  = (const float*)d_in[6];
  const float* b2  = (const float*)d_in[7];
  const float* g2  = (const float*)d_in[8];
  const float* be2 = (const float*)d_in[9];
  const float* W3  = (const float*)d_in[10];
  const float* b3  = (const float*)d_in[11];
  const float* g3  = (const float*)d_in[12];
  const float* be3 = (const float*)d_in[13];
  const float* Wp  = (const float*)d_in[14];
  const float* bp  = (const float*)d_in[15];
  const float* gp  = (const float*)d_in[16];
  const float* bep = (const float*)d_in[17];
  const float* Wf  = (const float*)d_in[18];
  const float* bf  = (const float*)d_in[19];

  float*  pooled = (float*)d_ws;                       // [128][256] f32, 128KB
  ushort* W3s    = (ushort*)((char*)d_ws + Bb * C3 * sizeof(float)); // 64KB

  hipMemsetAsync(pooled, 0, Bb * C3 * sizeof(float), stream);
  prepW3<<<128, 256, 0, stream>>>(W3, W3s);
  stageA<<<Bb * BLK_PER_BATCH, 256, 0, stream>>>(
      pc, W1, b1, g1, be1, W2, b2, g2, be2, W3s, b3, g3, be3, pooled);
  stageB<<<Bb, 256, 0, stream>>>(pooled, img, Wp, bp, gp, bep, Wf, bf,
                                 (float*)d_out);
}

// Round 4
// 1227.167 us; speedup vs baseline: 1.0332x; 1.0332x over previous
//
#include <hip/hip_runtime.h>

#define EPS 1e-5f

constexpr int Bb  = 128;     // batches
constexpr int Np  = 8192;    // points per batch
constexpr int C1  = 64, C2 = 128, C3 = 256;
constexpr int P   = 64;      // points per chunk (one 16-row M-tile per wave)
constexpr int CHUNKS = 4;    // chunks per block
constexpr int PTS_PER_BLOCK = P * CHUNKS;          // 256
constexpr int BLK_PER_BATCH = Np / PTS_PER_BLOCK;  // 32

typedef __attribute__((ext_vector_type(8))) short short8v;  // 8 bf16 = 4 VGPR
typedef __attribute__((ext_vector_type(4))) float f32x4;    // MFMA acc

__device__ __forceinline__ ushort f2bf(float f) {
  uint x = __float_as_uint(f);
  return (ushort)((x + 0x7fffu + ((x >> 16) & 1u)) >> 16);   // RNE
}

// ---------------------------------------------------------------------------
// prepW: pack W2 [64][128] and W3 [128][256] (f32) into bf16 B-fragments for
// v_mfma_f32_16x16x32_bf16.  Frag order: [tile][kk][lane][i] with
// k = kk*32 + (lane>>4)*8 + i,  n = tile*16 + (lane&15).
// W2s: 8 tiles x 2 kk = 8192 ushorts.  W3s: 16 tiles x 4 kk = 32768 ushorts.
// ---------------------------------------------------------------------------
__global__ __launch_bounds__(256) void prepW(const float* __restrict__ W2,
                                             const float* __restrict__ W3,
                                             ushort* __restrict__ W2s,
                                             ushort* __restrict__ W3s) {
  const int idx = blockIdx.x * 256 + threadIdx.x;   // 0..40959
  if (idx < 8192) {
    const int i  = idx & 7;
    const int l  = (idx >> 3) & 63;
    const int kk = (idx >> 9) & 1;
    const int t  = idx >> 10;
    const int k  = kk * 32 + (l >> 4) * 8 + i;
    const int n  = t * 16 + (l & 15);
    W2s[idx] = f2bf(W2[k * C2 + n]);
  } else {
    const int j  = idx - 8192;                      // 0..32767
    const int i  = j & 7;
    const int l  = (j >> 3) & 63;
    const int kk = (j >> 9) & 3;
    const int nt = j >> 11;
    const int k  = kk * 32 + (l >> 4) * 8 + i;
    const int n  = nt * 16 + (l & 15);
    W3s[j] = f2bf(W3[k * C3 + n]);
  }
}

// ---------------------------------------------------------------------------
// Stage A.  Per chunk of 64 points:
//   L1 (3->64):   fp32 VALU. lane handles point (lane&15), chans (lane>>4)*16+j.
//                 LN = 2 shfl_xor. h1 -> per-wave LDS region, bf16, swizzled.
//                 Wave-private: NO barrier between L1 and L2.
//   L2 (64->128): MFMA, M=16 (wave's rows) N=128 K=64 = 16 MFMA. LN in-wave
//                 (4-step shfl over 16-lane col group). h2 -> shared LDS.
//   L3 (128->256): MFMA, M=64 N=64/wave K=128 = 64 MFMA. LN cross-wave via
//                 s_red (3 barriers/chunk). ReLU + running max in registers.
// LDS layout: byte(row,col) = row*stride + (2*col ^ ((row&7)<<4)).
// ---------------------------------------------------------------------------
__global__ __launch_bounds__(256, 2) void stageA(
    const float* __restrict__ pc,
    const float* __restrict__ W1, const float* __restrict__ b1,
    const float* __restrict__ g1, const float* __restrict__ be1,
    const ushort* __restrict__ W2s, const float* __restrict__ b2,
    const float* __restrict__ g2, const float* __restrict__ be2,
    const ushort* __restrict__ W3s, const float* __restrict__ b3,
    const float* __restrict__ g3, const float* __restrict__ be3,
    float* __restrict__ pooled)      // [B][C3], pre-zeroed, int-bits atomicMax
{
  __shared__ __align__(16) ushort s_h1[4 * 16 * 64];  // 8KB, per-wave [16][64]
  __shared__ __align__(16) ushort s_h2[64 * 128];     // 16KB, [64][128]
  __shared__ float  s_red[4][64][2];                  // per-wave LN3 partials
  __shared__ float2 s_mi[64];                         // per-row (mean, inv)

  const int tid  = threadIdx.x;
  const int lane = tid & 63;
  const int w    = tid >> 6;
  const int lrow = lane & 15;        // A-row / C-D col index
  const int lgrp = lane >> 4;
  const int b    = blockIdx.x >> 5;                  // /32
  const int base_pt = (blockIdx.x & 31) * PTS_PER_BLOCK;

  // --- persistent: W3 B-frags (wave's 4 N-tiles), L3 per-col params ---
  short8v w3f[4][4];                  // [t][kk] = 64 VGPR
#pragma unroll
  for (int t = 0; t < 4; ++t)
#pragma unroll
    for (int kk = 0; kk < 4; ++kk)
      w3f[t][kk] = *(const short8v*)(W3s + (size_t)(((w * 4 + t) * 4 + kk) * 64 + lane) * 8);

  float b3c[4], g3c[4], e3c[4];
#pragma unroll
  for (int t = 0; t < 4; ++t) {
    const int col = w * 64 + t * 16 + lrow;
    b3c[t] = b3[col]; g3c[t] = g3[col]; e3c[t] = be3[col];
  }

  float runmax[4] = {0.f, 0.f, 0.f, 0.f};

  char* const h1b = (char*)s_h1 + w * 2048;   // wave-private 16x64 bf16 region
  const int sw1 = (lrow & 7) << 4;

  for (int ch = 0; ch < CHUNKS; ++ch) {
    // ================= layer 1: 3 -> 64, fp32 VALU =================
    const float* xp = pc + (size_t)(b * Np + base_pt + ch * P + w * 16 + lrow) * 3;
    const float x0 = xp[0], x1 = xp[1], x2 = xp[2];
    float y[16];
#pragma unroll
    for (int j = 0; j < 16; ++j) {
      const int c = lgrp * 16 + j;
      y[j] = x0 * W1[c] + x1 * W1[C1 + c] + x2 * W1[2 * C1 + c] + b1[c];
    }
    float s1 = 0.f, q1 = 0.f;
#pragma unroll
    for (int j = 0; j < 16; ++j) { s1 += y[j]; q1 += y[j] * y[j]; }
    s1 += __shfl_xor(s1, 16, 64); q1 += __shfl_xor(q1, 16, 64);
    s1 += __shfl_xor(s1, 32, 64); q1 += __shfl_xor(q1, 32, 64);
    const float m1 = s1 * (1.f / 64.f);
    const float i1 = rsqrtf(q1 * (1.f / 64.f) - m1 * m1 + EPS);
    uint pk[8];
#pragma unroll
    for (int j2 = 0; j2 < 8; ++j2) {
      const int c0 = lgrp * 16 + 2 * j2;
      const float h0 = fmaxf((y[2 * j2]     - m1) * i1 * g1[c0]     + be1[c0],     0.f);
      const float h1 = fmaxf((y[2 * j2 + 1] - m1) * i1 * g1[c0 + 1] + be1[c0 + 1], 0.f);
      pk[j2] = (uint)f2bf(h0) | ((uint)f2bf(h1) << 16);
    }
    {
      const int base = lrow * 128 + lgrp * 32;   // bytes; two 16B blocks
      *(uint4*)(h1b + ((base     ) ^ sw1)) = make_uint4(pk[0], pk[1], pk[2], pk[3]);
      *(uint4*)(h1b + ((base + 16) ^ sw1)) = make_uint4(pk[4], pk[5], pk[6], pk[7]);
    }
    // wave-private region: compiler-inserted lgkmcnt orders write->read.

    // ================= layer 2: 64 -> 128, MFMA =================
    short8v a2[2];
#pragma unroll
    for (int kk = 0; kk < 2; ++kk)
      a2[kk] = *(const short8v*)(h1b + ((lrow * 128 + (kk * 64 + lgrp * 16)) ^ sw1));

    f32x4 acc2[8];
#pragma unroll
    for (int t = 0; t < 8; ++t) {
      acc2[t] = (f32x4){0.f, 0.f, 0.f, 0.f};
#pragma unroll
      for (int kk = 0; kk < 2; ++kk) {
        const short8v w2f = *(const short8v*)(W2s + (size_t)((t * 2 + kk) * 64 + lane) * 8);
        acc2[t] = __builtin_amdgcn_mfma_f32_16x16x32_bf16(a2[kk], w2f, acc2[t], 0, 0, 0);
      }
    }

    // LN2 (in-wave): rows w*16 + lgrp*4 + j, cols 16t + lrow
    float s2[4] = {0.f,0.f,0.f,0.f}, q2[4] = {0.f,0.f,0.f,0.f};
    float b2v[8], g2v[8], e2v[8];
#pragma unroll
    for (int t = 0; t < 8; ++t) {
      const int col = t * 16 + lrow;
      b2v[t] = b2[col]; g2v[t] = g2[col]; e2v[t] = be2[col];
    }
#pragma unroll
    for (int t = 0; t < 8; ++t)
#pragma unroll
      for (int j = 0; j < 4; ++j) {
        const float v = acc2[t][j] + b2v[t];
        acc2[t][j] = v;
        s2[j] += v; q2[j] += v * v;
      }
#pragma unroll
    for (int m = 1; m < 16; m <<= 1)
#pragma unroll
      for (int j = 0; j < 4; ++j) {
        s2[j] += __shfl_xor(s2[j], m, 64);
        q2[j] += __shfl_xor(q2[j], m, 64);
      }
#pragma unroll
    for (int j = 0; j < 4; ++j) {
      const float m2 = s2[j] * (1.f / 128.f);
      const float i2 = rsqrtf(q2[j] * (1.f / 128.f) - m2 * m2 + EPS);
      const int row = w * 16 + lgrp * 4 + j;
      const int swr = (row & 7) << 4;
#pragma unroll
      for (int t = 0; t < 8; ++t) {
        const float h = fmaxf((acc2[t][j] - m2) * i2 * g2v[t] + e2v[t], 0.f);
        *(ushort*)((char*)s_h2 + row * 256 + ((t * 32 + lrow * 2) ^ swr)) = f2bf(h);
      }
    }
    __syncthreads();   // B1: h2 visible to all waves

    // ================= layer 3: 128 -> 256, MFMA =================
    f32x4 acc3[4][4];  // [g][t]
#pragma unroll
    for (int g = 0; g < 4; ++g) {
      short8v a3[4];
      const int row = g * 16 + lrow;
      const int rb  = row * 256;
      const int swr = (row & 7) << 4;
#pragma unroll
      for (int kk = 0; kk < 4; ++kk)
        a3[kk] = *(const short8v*)((const char*)s_h2 + rb + ((kk * 64 + lgrp * 16) ^ swr));
#pragma unroll
      for (int t = 0; t < 4; ++t) {
        acc3[g][t] = (f32x4){0.f, 0.f, 0.f, 0.f};
#pragma unroll
        for (int kk = 0; kk < 4; ++kk)
          acc3[g][t] = __builtin_amdgcn_mfma_f32_16x16x32_bf16(a3[kk], w3f[t][kk], acc3[g][t], 0, 0, 0);
      }
    }

    // bias + LN3 stats (rows g*16 + lgrp*4 + j)
    float sp[4][4], sq[4][4];
#pragma unroll
    for (int g = 0; g < 4; ++g)
#pragma unroll
      for (int j = 0; j < 4; ++j) { sp[g][j] = 0.f; sq[g][j] = 0.f; }
#pragma unroll
    for (int g = 0; g < 4; ++g)
#pragma unroll
      for (int t = 0; t < 4; ++t)
#pragma unroll
        for (int j = 0; j < 4; ++j) {
          const float v = acc3[g][t][j] + b3c[t];
          acc3[g][t][j] = v;
          sp[g][j] += v; sq[g][j] += v * v;
        }
#pragma unroll
    for (int m = 1; m < 16; m <<= 1)
#pragma unroll
      for (int g = 0; g < 4; ++g)
#pragma unroll
        for (int j = 0; j < 4; ++j) {
          sp[g][j] += __shfl_xor(sp[g][j], m, 64);
          sq[g][j] += __shfl_xor(sq[g][j], m, 64);
        }
    if (lrow == 0) {
#pragma unroll
      for (int g = 0; g < 4; ++g)
#pragma unroll
        for (int j = 0; j < 4; ++j) {
          const int row = g * 16 + lgrp * 4 + j;
          s_red[w][row][0] = sp[g][j];
          s_red[w][row][1] = sq[g][j];
        }
    }
    __syncthreads();   // B2
    if (tid < 64) {
      const float ss = s_red[0][tid][0] + s_red[1][tid][0] + s_red[2][tid][0] + s_red[3][tid][0];
      const float qq = s_red[0][tid][1] + s_red[1][tid][1] + s_red[2][tid][1] + s_red[3][tid][1];
      const float mean = ss * (1.f / 256.f);
      s_mi[tid] = make_float2(mean, rsqrtf(qq * (1.f / 256.f) - mean * mean + EPS));
    }
    __syncthreads();   // B3

#pragma unroll
    for (int g = 0; g < 4; ++g)
#pragma unroll
      for (int j = 0; j < 4; ++j) {
        const float2 mi = s_mi[g * 16 + lgrp * 4 + j];
#pragma unroll
        for (int t = 0; t < 4; ++t) {
          const float h = fmaxf((acc3[g][t][j] - mi.x) * mi.y * g3c[t] + e3c[t], 0.f);
          runmax[t] = fmaxf(runmax[t], h);
        }
      }
  }

  // ---- col max across lanes sharing lrow, then global atomic ----
#pragma unroll
  for (int t = 0; t < 4; ++t) {
    float v = runmax[t];
    v = fmaxf(v, __shfl_xor(v, 16, 64));
    v = fmaxf(v, __shfl_xor(v, 32, 64));
    if (lane < 16)
      atomicMax((int*)&pooled[b * C3 + w * 64 + t * 16 + lane], __float_as_int(v));
  }
}

// ---------------------------------------------------------------------------
// Stage B: pooled -> LN(pooled@Wp+bp) -> film = pc@Wf+bf -> out = s*img + b
// ---------------------------------------------------------------------------
__global__ __launch_bounds__(256) void stageB(
    const float* __restrict__ pooled,  // [B][256]
    const float* __restrict__ img,     // [B][512]
    const float* __restrict__ Wp, const float* __restrict__ bp,
    const float* __restrict__ gp, const float* __restrict__ bep,
    const float* __restrict__ Wf, const float* __restrict__ bf,
    float* __restrict__ out)           // [B][512]
{
  __shared__ float s_pool[C3];
  __shared__ float s_pc[C3];
  __shared__ float s_red[8];

  const int t = threadIdx.x, b = blockIdx.x;
  const int lane = t & 63, w = t >> 6;

  s_pool[t] = pooled[b * C3 + t];
  __syncthreads();

  float y = bp[t];
  for (int k = 0; k < C3; ++k) y += s_pool[k] * Wp[k * C3 + t];

  float s = y, q = y * y;
  for (int m = 1; m < 64; m <<= 1) { s += __shfl_xor(s, m, 64); q += __shfl_xor(q, m, 64); }
  if (lane == 0) { s_red[w * 2] = s; s_red[w * 2 + 1] = q; }
  __syncthreads();
  s = s_red[0] + s_red[2] + s_red[4] + s_red[6];
  q = s_red[1] + s_red[3] + s_red[5] + s_red[7];
  const float mean = s * (1.f / 256.f);
  const float var  = q * (1.f / 256.f) - mean * mean;
  const float inv  = rsqrtf(var + EPS);
  s_pc[t] = (y - mean) * inv * gp[t] + bep[t];
  __syncthreads();

  float f0 = bf[t], f1 = bf[256 + t], f2 = bf[512 + t], f3 = bf[768 + t];
  for (int k = 0; k < C3; ++k) {
    const float pv = s_pc[k];
    f0 += pv * Wf[k * 1024 + t];
    f1 += pv * Wf[k * 1024 + 256 + t];
    f2 += pv * Wf[k * 1024 + 512 + t];
    f3 += pv * Wf[k * 1024 + 768 + t];
  }
  out[b * 512 + t]       = f0 * img[b * 512 + t]       + f2;
  out[b * 512 + 256 + t] = f1 * img[b * 512 + 256 + t] + f3;
}

extern "C" void kernel_launch(void* const* d_in, const int* in_sizes, int n_in,
                              void* d_out, int out_size, void* d_ws, size_t ws_size,
                              hipStream_t stream) {
  const float* pc  = (const float*)d_in[0];
  const float* img = (const float*)d_in[1];
  const float* W1  = (const float*)d_in[2];
  const float* b1  = (const float*)d_in[3];
  const float* g1  = (const float*)d_in[4];
  const float* be1 = (const float*)d_in[5];
  const float* W2  = (const float*)d_in[6];
  const float* b2  = (const float*)d_in[7];
  const float* g2  = (const float*)d_in[8];
  const float* be2 = (const float*)d_in[9];
  const float* W3  = (const float*)d_in[10];
  const float* b3  = (const float*)d_in[11];
  const float* g3  = (const float*)d_in[12];
  const float* be3 = (const float*)d_in[13];
  const float* Wp  = (const float*)d_in[14];
  const float* bp  = (const float*)d_in[15];
  const float* gp  = (const float*)d_in[16];
  const float* bep = (const float*)d_in[17];
  const float* Wf  = (const float*)d_in[18];
  const float* bf  = (const float*)d_in[19];

  float*  pooled = (float*)d_ws;                                   // 128 KB
  ushort* W2s = (ushort*)((char*)d_ws + Bb * C3 * sizeof(float));  // 16 KB
  ushort* W3s = W2s + 8192;                                        // 64 KB

  hipMemsetAsync(pooled, 0, Bb * C3 * sizeof(float), stream);
  prepW<<<160, 256, 0, stream>>>(W2, W3, W2s, W3s);
  stageA<<<Bb * BLK_PER_BATCH, 256, 0, stream>>>(
      pc, W1, b1, g1, be1, W2s, b2, g2, be2, W3s, b3, g3, be3, pooled);
  stageB<<<Bb, 256, 0, stream>>>(pooled, img, Wp, bp, gp, bep, Wf, bf,
                                 (float*)d_out);
}